// Round 2
// baseline (1089.006 us; speedup 1.0000x reference)
//
#include <hip/hip_runtime.h>
#include <stdint.h>

// Problem constants (B=4, S=4096, F=4096, O=4096, CHUNKS=4)
static constexpr int M = 16384;     // B*S rows of x
static constexpr int N = 4096;      // O
static constexpr int K = 4096;      // F
static constexpr int NCHUNK = 4;
static constexpr int CHUNK = 1024;  // K / NCHUNK

// GEMM tiling
static constexpr int BM = 256, BN = 128, BK = 128;   // BK in bytes (i8)
static constexpr int ABYTES = BM * BK;               // 32768
static constexpr int BBYTES = BN * BK;               // 16384
static constexpr int BUFB = ABYTES + BBYTES;         // 49152 per K-tile
static constexpr int NSTEP = K / BK;                 // 32
static constexpr int STEPS_PER_CHUNK = CHUNK / BK;   // 8

#define QMAXF 127.0f
#define EPSF 1e-8f

using i32x4 = __attribute__((ext_vector_type(4))) int;
using f32x4 = __attribute__((ext_vector_type(4))) float;

__device__ __forceinline__ void gld_lds16(const void* g, void* l) {
  __builtin_amdgcn_global_load_lds((const __attribute__((address_space(1))) void*)g,
                                   (__attribute__((address_space(3))) void*)l,
                                   16, 0, 0);
}

__device__ __forceinline__ float scale_from_bits(unsigned bits) {
  return fmaxf(__uint_as_float(bits) / QMAXF, EPSF);
}

__device__ __forceinline__ unsigned quant_pack4(float4 v, float inv) {
  int q0 = (int)fminf(fmaxf(rintf(v.x * inv), -QMAXF), QMAXF);
  int q1 = (int)fminf(fmaxf(rintf(v.y * inv), -QMAXF), QMAXF);
  int q2 = (int)fminf(fmaxf(rintf(v.z * inv), -QMAXF), QMAXF);
  int q3 = (int)fminf(fmaxf(rintf(v.w * inv), -QMAXF), QMAXF);
  return (unsigned)(q0 & 0xff) | ((unsigned)(q1 & 0xff) << 8) |
         ((unsigned)(q2 & 0xff) << 16) | ((unsigned)(q3 & 0xff) << 24);
}

// ---------------------------------------------------------------- absmax
// One kernel, 5 planes via blockIdx.y: p=0..3 -> x chunk p, p=4 -> w.
// Each plane is exactly 4,194,304 float4 (64 MB). Chunk id comes from the
// grid so the reduction is a single running max (no predicated 4-way max,
// no runtime-indexed arrays). Each block streams whole 4 KB row-chunks.
__global__ void absmax_kernel(const float* __restrict__ x, const float* __restrict__ w,
                              unsigned* __restrict__ scales) {
  const int p = blockIdx.y;
  const int tid = blockIdx.x * blockDim.x + threadIdx.x;
  const int stride = gridDim.x * blockDim.x;
  const int total = (N * K) / 4;  // 4,194,304 float4 per plane
  float m = 0.f;
  if (p == 4) {
    const float4* w4 = (const float4*)w;
    for (int i = tid; i < total; i += stride) {
      float4 v = w4[i];
      m = fmaxf(m, fmaxf(fmaxf(fabsf(v.x), fabsf(v.y)), fmaxf(fabsf(v.z), fabsf(v.w))));
    }
  } else {
    const float4* x4 = (const float4*)x;
    for (int i = tid; i < total; i += stride) {
      const int r = i >> 8, j = i & 255;  // row, f4-within-chunk
      float4 v = x4[((size_t)r << 10) + (p << 8) + j];
      m = fmaxf(m, fmaxf(fmaxf(fabsf(v.x), fabsf(v.y)), fmaxf(fabsf(v.z), fabsf(v.w))));
    }
  }
  #pragma unroll
  for (int off = 32; off; off >>= 1) m = fmaxf(m, __shfl_down(m, off));
  __shared__ float sm[4];
  const int lane = threadIdx.x & 63, wv = threadIdx.x >> 6;
  if (lane == 0) sm[wv] = m;
  __syncthreads();
  if (threadIdx.x == 0) {
    m = fmaxf(fmaxf(sm[0], sm[1]), fmaxf(sm[2], sm[3]));
    atomicMax(scales + (p == 4 ? 0 : 1 + p), __float_as_uint(m));
  }
}

// ---------------------------------------------------------------- quantize
// Same 5-plane layout; inv is a wave-uniform scalar per block (no scratch
// array, no per-element chunk decode).
__global__ void quant_kernel(const float* __restrict__ x, const float* __restrict__ w,
                             const unsigned* __restrict__ scales,
                             char* __restrict__ xq, char* __restrict__ wq) {
  const int p = blockIdx.y;
  const int tid = blockIdx.x * blockDim.x + threadIdx.x;
  const int stride = gridDim.x * blockDim.x;
  const int total = (N * K) / 4;
  const float inv = 1.0f / scale_from_bits(scales[p == 4 ? 0 : 1 + p]);
  if (p == 4) {
    const float4* w4 = (const float4*)w;
    unsigned* wq4 = (unsigned*)wq;
    for (int i = tid; i < total; i += stride) wq4[i] = quant_pack4(w4[i], inv);
  } else {
    const float4* x4 = (const float4*)x;
    unsigned* xq4 = (unsigned*)xq;
    for (int i = tid; i < total; i += stride) {
      const int r = i >> 8, j = i & 255;
      const size_t idx = ((size_t)r << 10) + (p << 8) + j;
      xq4[idx] = quant_pack4(x4[idx], inv);
    }
  }
}

// ------------------------------------------------------------ int8 GEMM
// 256x128 tile, 512 threads (8 waves as 4M x 2N), per-wave 64x64 output,
// BK=128 bytes per K-step, 32 K-steps, chunk fold every 8 steps.
//
// Grid = 64 M-tiles x 32 N-tiles = 2048 blocks.  (Round-1 crash: decoded
// this as 128x16 -> rows up to 32767 -> OOB fault. Fixed: &31 / >>5.)
//
// Schedule (T3+T4+T5): triple-buffered LDS (tile u -> buf u%3). Loads for
// tile t+2 are issued during step t; each step does
//    s_waitcnt lgkmcnt(0) (program-order guarantee: this wave's ds_reads of
//                          buf[(t-1)%3] are complete before it can be reclaimed)
//    s_waitcnt vmcnt(6)   (6 newer loads = tile t+1's stay in flight)
//    s_barrier            (raw: no vmcnt drain)
//    issue 6 global_load_lds for tile t+2 into buf[(t-1)%3]
//    ds_read frags + MFMA (setprio(1) around MFMA clusters)
// WAR safety: tile t+2 overwrites buf[(t-1)%3]; every wave's reads of that
// buffer completed (lgkmcnt(0) above) before the barrier at t released it.
// Last two steps: no prefetch; final step waits vmcnt(0).
//
// LDS swizzle: global 16B k-block col of row r stored at col^(r&7); read side
// applies the same XOR -> a quad's 16 lanes spread over all 32 banks at
// 2 lanes/bank (free, m136). Staging bakes the inverse permutation into the
// per-lane *global* source address (global_load_lds LDS side must be linear;
// per-wave dst is base + lane*16, which our slot map satisfies).
__global__ __launch_bounds__(512, 2)
void gemm_i8_kernel(const char* __restrict__ xq, const char* __restrict__ wq,
                    const float* __restrict__ bias, const unsigned* __restrict__ scales,
                    float* __restrict__ out) {
  __shared__ char lds[3 * BUFB];  // 147456 B

  // XCD-aware swizzle (nwg=2048, %8==0 -> bijective). tn fastest within an
  // XCD chunk so 32 consecutive blocks share one A panel (1 MB, L2-resident).
  const int bid = blockIdx.x;
  const int swz = (bid & 7) * 256 + (bid >> 3);
  const int tn = swz & 31;   // 0..31  (N tiles)
  const int tm = swz >> 5;   // 0..63  (M tiles)

  const int t = threadIdx.x;
  const int lane = t & 63, wv = t >> 6;
  const int wr = wv >> 1, wc = wv & 1;       // wave grid 4M x 2N
  const int l16 = lane & 15, quad = lane >> 4;

  const float wsc = scale_from_bits(scales[0]);
  float csc[NCHUNK];
  #pragma unroll
  for (int c = 0; c < NCHUNK; ++c) csc[c] = scale_from_bits(scales[1 + c]) * wsc;

  // Staging: A = 2048 16B slots, B = 1024 slots; thread t owns A slots
  // t+j*512 (j=0..3) and B slots t+j*512 (j=0..1). Slot L -> row L>>3,
  // LDS col L&7, global col (L&7)^((L>>3)&7).
  const char* aSrc[4]; unsigned aDst[4];
  #pragma unroll
  for (int j = 0; j < 4; ++j) {
    const int L = t + j * 512;
    const int row = L >> 3, colG = (L & 7) ^ (row & 7);
    aSrc[j] = xq + (size_t)(tm * 256 + row) * K + colG * 16;
    aDst[j] = (unsigned)(L * 16);
  }
  const char* bSrc[2]; unsigned bDst[2];
  #pragma unroll
  for (int j = 0; j < 2; ++j) {
    const int L = t + j * 512;
    const int row = L >> 3, colG = (L & 7) ^ (row & 7);
    bSrc[j] = wq + (size_t)(tn * 128 + row) * K + colG * 16;
    bDst[j] = (unsigned)(ABYTES + L * 16);
  }

  // Read-side swizzled fragment offsets (16x16x64: row=l16, k-16B-block=quad).
  unsigned aoffs[2], boffs[2];
  #pragma unroll
  for (int kf = 0; kf < 2; ++kf) {
    const unsigned cs = (unsigned)((((kf * 4 + quad) ^ (l16 & 7)) * 16));
    aoffs[kf] = (unsigned)((wr * 64 + l16) * BK) + cs;
    boffs[kf] = (unsigned)(ABYTES + (wc * 64 + l16) * BK) + cs;
  }

  auto issue = [&](unsigned bufOff) {
    #pragma unroll
    for (int j = 0; j < 4; ++j) gld_lds16(aSrc[j], lds + bufOff + aDst[j]);
    #pragma unroll
    for (int j = 0; j < 2; ++j) gld_lds16(bSrc[j], lds + bufOff + bDst[j]);
    #pragma unroll
    for (int j = 0; j < 4; ++j) aSrc[j] += BK;
    #pragma unroll
    for (int j = 0; j < 2; ++j) bSrc[j] += BK;
  };

  f32x4 facc[4][4];
  #pragma unroll
  for (int mi = 0; mi < 4; ++mi)
    #pragma unroll
    for (int ni = 0; ni < 4; ++ni) facc[mi][ni] = (f32x4)(0.f);

  // Prologue: tiles 0 and 1 in flight.
  issue(0);
  issue(BUFB);
  unsigned pfOff = 2 * BUFB;  // tile 2 target
  unsigned rdOff = 0;         // tile 0

  #pragma unroll
  for (int c = 0; c < NCHUNK; ++c) {
    i32x4 iacc[4][4];
    #pragma unroll
    for (int mi = 0; mi < 4; ++mi)
      #pragma unroll
      for (int ni = 0; ni < 4; ++ni) iacc[mi][ni] = (i32x4)(0);

    #pragma unroll 1
    for (int kk = 0; kk < STEPS_PER_CHUNK; ++kk) {
      const int tt = c * STEPS_PER_CHUNK + kk;
      asm volatile("s_waitcnt lgkmcnt(0)" ::: "memory");
      if (tt < NSTEP - 1) {
        asm volatile("s_waitcnt vmcnt(6)" ::: "memory");
      } else {
        asm volatile("s_waitcnt vmcnt(0)" ::: "memory");
      }
      __builtin_amdgcn_s_barrier();
      asm volatile("" ::: "memory");  // no LDS ops hoisted above the barrier

      if (tt <= NSTEP - 3) {
        issue(pfOff);
        pfOff = (pfOff == 2 * BUFB) ? 0u : pfOff + BUFB;
      }

      #pragma unroll
      for (int kf = 0; kf < 2; ++kf) {
        i32x4 af[4], bf[4];
        #pragma unroll
        for (int mi = 0; mi < 4; ++mi)
          af[mi] = *(const i32x4*)(lds + rdOff + aoffs[kf] + mi * (16 * BK));
        #pragma unroll
        for (int ni = 0; ni < 4; ++ni)
          bf[ni] = *(const i32x4*)(lds + rdOff + boffs[kf] + ni * (16 * BK));
        __builtin_amdgcn_s_setprio(1);
        #pragma unroll
        for (int mi = 0; mi < 4; ++mi)
          #pragma unroll
          for (int ni = 0; ni < 4; ++ni)
            iacc[mi][ni] = __builtin_amdgcn_mfma_i32_16x16x64_i8(af[mi], bf[ni], iacc[mi][ni], 0, 0, 0);
        __builtin_amdgcn_s_setprio(0);
      }
      rdOff = (rdOff == 2 * BUFB) ? 0u : rdOff + BUFB;
    }

    const float sc = csc[c];
    #pragma unroll
    for (int mi = 0; mi < 4; ++mi)
      #pragma unroll
      for (int ni = 0; ni < 4; ++ni)
        #pragma unroll
        for (int e = 0; e < 4; ++e)
          facc[mi][ni][e] += sc * (float)iacc[mi][ni][e];
  }

  // Epilogue: C/D layout (16x16 family): col = lane&15, row = quad*4 + reg.
  #pragma unroll
  for (int ni = 0; ni < 4; ++ni) {
    const int col = tn * 128 + wc * 64 + ni * 16 + l16;
    const float bv = bias[col];
    #pragma unroll
    for (int mi = 0; mi < 4; ++mi) {
      const int row_base = tm * 256 + wr * 64 + mi * 16 + quad * 4;
      #pragma unroll
      for (int e = 0; e < 4; ++e)
        out[(size_t)(row_base + e) * N + col] = facc[mi][ni][e] + bv;
    }
  }
}

extern "C" void kernel_launch(void* const* d_in, const int* in_sizes, int n_in,
                              void* d_out, int out_size, void* d_ws, size_t ws_size,
                              hipStream_t stream) {
  const float* x = (const float*)d_in[0];     // [4,4096,4096] fp32
  const float* w = (const float*)d_in[1];     // [4096,4096] fp32
  const float* bias = (const float*)d_in[2];  // [4096] fp32
  float* out = (float*)d_out;                 // [4,4096,4096] fp32

  unsigned* scales = (unsigned*)d_ws;         // [0]=w absmax bits, [1..4]=x chunk absmax bits
  char* xq = (char*)d_ws + 64;                // 64 MB int8
  char* wq = xq + (size_t)M * K;              // 16 MB int8

  hipMemsetAsync(d_ws, 0, 64, stream);

  dim3 pgrid(2048, 5);
  absmax_kernel<<<pgrid, 256, 0, stream>>>(x, w, scales);
  quant_kernel<<<pgrid, 256, 0, stream>>>(x, w, scales, xq, wq);

  gemm_i8_kernel<<<dim3(2048), 512, 0, stream>>>(xq, wq, bias, scales, out);
}